// Round 1
// 1678.752 us; speedup vs baseline: 1.4346x; 1.4346x over previous
//
#include <hip/hip_runtime.h>
#include <cstdint>

typedef unsigned short u16;
typedef __attribute__((ext_vector_type(8))) short bf16x8;   // 8 bf16 = 4 VGPRs (MFMA A/B frag)
typedef __attribute__((ext_vector_type(8))) u16  u16x8;
typedef __attribute__((ext_vector_type(4))) float f32x4;    // MFMA C/D frag

constexpr int TM = 8192;    // tokens (M)
constexpr int TK = 4096;    // in_features (K)
constexpr int TN = 16384;   // out_features (N)

// ---------------- 256x256 8-phase GEMM params ----------------
#define BK2 64
constexpr int NT  = TK / BK2;   // 64 K-tiles
constexpr int NIT = NT / 2;     // 32 iterations, 2 K-tiles each
static_assert(NT % 2 == 0, "NT must be even");

// fp32 -> bf16 round-to-nearest-even (inputs are finite normals; no NaN path needed)
__device__ __forceinline__ u16 f2bf(float f) {
  union { float f; unsigned int u; } v; v.f = f;
  unsigned int u = v.u;
  return (u16)((u + 0x7fffu + ((u >> 16) & 1u)) >> 16);
}

// async global->LDS, 16B per lane. LDS dest is wave-uniform base + lane*16,
// so the chunk id must be lane-contiguous in thread order (it is: j = issue*512 + t).
__device__ __forceinline__ void cp16_g2l(const u16* g, u16* l) {
  __builtin_amdgcn_global_load_lds(
      (const __attribute__((address_space(1))) unsigned int*)g,
      (__attribute__((address_space(3))) unsigned int*)l,
      16, 0, 0);
}

// ---------------- conversion pre-passes ----------------
__global__ __launch_bounds__(256) void cvt_x_kernel(const float* __restrict__ src,
                                                    u16* __restrict__ dst) {
  size_t i = ((size_t)blockIdx.x * 256 + threadIdx.x) * 8;
  float4 v0 = *(const float4*)(src + i);
  float4 v1 = *(const float4*)(src + i + 4);
  u16x8 o;
  o[0] = f2bf(v0.x); o[1] = f2bf(v0.y); o[2] = f2bf(v0.z); o[3] = f2bf(v0.w);
  o[4] = f2bf(v1.x); o[5] = f2bf(v1.y); o[6] = f2bf(v1.z); o[7] = f2bf(v1.w);
  *(u16x8*)(dst + i) = o;
}

__global__ __launch_bounds__(256) void cvt_w_kernel(const int* __restrict__ src,
                                                    u16* __restrict__ dst) {
  size_t i = ((size_t)blockIdx.x * 256 + threadIdx.x) * 8;
  int4 v0 = *(const int4*)(src + i);
  int4 v1 = *(const int4*)(src + i + 4);
  // |v| <= 127: exact in bf16
  u16x8 o;
  o[0] = f2bf((float)v0.x); o[1] = f2bf((float)v0.y); o[2] = f2bf((float)v0.z); o[3] = f2bf((float)v0.w);
  o[4] = f2bf((float)v1.x); o[5] = f2bf((float)v1.y); o[6] = f2bf((float)v1.z); o[7] = f2bf((float)v1.w);
  *(u16x8*)(dst + i) = o;
}

// ============================================================================
// 256x256 8-phase GEMM  (learn_hip m201 template: T1+T2+T3+T4+T5)
//
// C[m][n] = scale * (sum_k x[m][k] * w[n][k] + bias[n])
//
// 512 threads = 8 waves (2 qm-halves x 4 qn-quarters). Per K-tile (BK=64) the
// whole block computes the four 128x128 C-quadrants in 4 phases:
//   p: Q(0,0) A0*B0 -> Q(0,1) A0*B1 -> Q(1,1) A1*B1 -> Q(1,0) A1*B0
// (A frags reused in regs across 2 phases, B1 likewise; B0 re-read at p4).
// LDS half-tile lifetimes therefore die progressively: A0 after p1, B1 after
// p2, A1 after p3, B0 after p4 -> stage exactly one half-tile per phase into
// the slot that died one phase earlier (>=1 barrier pair in between = WAR-safe).
// Issue-order induction: at phases 4/8, vmcnt(6) completes exactly the 4
// half-tiles of the next K-tile and leaves 3 half-tiles (6 loads) in flight
// across the barrier -- never drains to 0 in the main loop (T4).
// Chunk-XOR swizzle (both-sides: pre-swizzled global src + XOR on ds_read)
// keeps ds_read_b128 at <=2-way bank aliasing (free).
// ============================================================================
__global__ __launch_bounds__(512, 2) void qlinear_gemm256(
    const u16* __restrict__ Abf, const u16* __restrict__ Bbf,
    const int* __restrict__ bias, const float* __restrict__ scalep,
    float* __restrict__ C) {
  // [buf 0/1][slot: 0=A0,1=A1,2=B0,3=B1][128 rows][64 k] bf16 = 128 KiB
  __shared__ __attribute__((aligned(16))) u16 lds[2 * 4 * 128 * 64];

  const int t    = threadIdx.x;
  const int lane = t & 63;
  const int wv   = t >> 6;   // 0..7
  const int wqm  = wv >> 2;  // 0..1 : 64-row band within a 128-row quadrant half
  const int wqn  = wv & 3;   // 0..3 : 32-col band within a 128-col quadrant half

  // XCD-aware swizzle: 2048 blocks, nwg % 8 == 0 -> simple form is bijective.
  // Each XCD gets a contiguous swz chunk => one A-panel reused across 64
  // consecutive resident blocks from its private L2.
  const int bid = (int)blockIdx.x;
  const int swz = (bid & 7) * 256 + (bid >> 3);
  const int bm  = (swz >> 6) * 256;  // M tile 0..31
  const int bn  = (swz & 63) * 256;  // N tile 0..63

  f32x4 acc[4][4][2];  // [quadrant qm*2+qn][mi][ni]
#pragma unroll
  for (int q = 0; q < 4; ++q)
#pragma unroll
    for (int mi = 0; mi < 4; ++mi)
#pragma unroll
      for (int ni = 0; ni < 2; ++ni) acc[q][mi][ni] = (f32x4){0.f, 0.f, 0.f, 0.f};

  bf16x8 af[4][2];   // A frags: 4 m x 2 k-halves
  bf16x8 bfr[2][2];  // B frags: 2 n x 2 k-halves

#define LDSB(BUF, SLOT) (lds + ((BUF) * 4 + (SLOT)) * (128 * 64))

// stage one half-tile (128 rows x 64 k) = 2 x global_load_lds_dwordx4 / thread.
// slot: 0=A0,1=A1,2=B0,3=B1. Global k-chunk pre-swizzled: phys chunk c of row r
// holds global chunk c ^ (r&7); LDS dest linear (wave-uniform base + lane*16).
#define STAGE(BUF, SLOT, TILE)                                                  \
  do {                                                                          \
    const u16* src_ = ((SLOT) < 2 ? Abf + (size_t)(bm + ((SLOT)&1) * 128) * TK  \
                                  : Bbf + (size_t)(bn + ((SLOT)&1) * 128) * TK) \
                      + (size_t)(TILE) * BK2;                                   \
    u16* dst_ = LDSB(BUF, SLOT);                                                \
    _Pragma("unroll") for (int is_ = 0; is_ < 2; ++is_) {                       \
      const int j_ = is_ * 512 + t; /* chunk id 0..1023 */                      \
      const int r_ = j_ >> 3;       /* row 0..127 */                            \
      const int g_ = (j_ & 7) ^ (r_ & 7);                                       \
      cp16_g2l(src_ + (size_t)r_ * TK + g_ * 8, dst_ + (size_t)j_ * 8);         \
    }                                                                           \
  } while (0)

#define READ_A(BUF, QM)                                                   \
  do {                                                                    \
    const u16* base_ = LDSB(BUF, QM);                                     \
    _Pragma("unroll") for (int mi = 0; mi < 4; ++mi) {                    \
      const int r_ = wqm * 64 + mi * 16 + (lane & 15);                    \
      _Pragma("unroll") for (int kk = 0; kk < 2; ++kk) {                  \
        const int px_ = (kk * 4 + (lane >> 4)) ^ (r_ & 7);                \
        af[mi][kk] = *(const bf16x8*)(base_ + r_ * 64 + px_ * 8);         \
      }                                                                   \
    }                                                                     \
  } while (0)

#define READ_B(BUF, QN)                                                   \
  do {                                                                    \
    const u16* base_ = LDSB(BUF, 2 + (QN));                               \
    _Pragma("unroll") for (int ni = 0; ni < 2; ++ni) {                    \
      const int r_ = wqn * 32 + ni * 16 + (lane & 15);                    \
      _Pragma("unroll") for (int kk = 0; kk < 2; ++kk) {                  \
        const int px_ = (kk * 4 + (lane >> 4)) ^ (r_ & 7);                \
        bfr[ni][kk] = *(const bf16x8*)(base_ + r_ * 64 + px_ * 8);        \
      }                                                                   \
    }                                                                     \
  } while (0)

#define MFMA_Q(QI)                                                              \
  do {                                                                          \
    __builtin_amdgcn_s_setprio(1);                                              \
    _Pragma("unroll") for (int mi = 0; mi < 4; ++mi)                            \
        _Pragma("unroll") for (int ni = 0; ni < 2; ++ni)                        \
            _Pragma("unroll") for (int kk = 0; kk < 2; ++kk)                    \
                acc[QI][mi][ni] = __builtin_amdgcn_mfma_f32_16x16x32_bf16(      \
                    af[mi][kk], bfr[ni][kk], acc[QI][mi][ni], 0, 0, 0);         \
    __builtin_amdgcn_s_setprio(0);                                              \
  } while (0)

#define BAR() __builtin_amdgcn_s_barrier()
// rule #18: fence the scheduler right after the inline-asm wait
#define LGK0()                                              \
  do {                                                      \
    asm volatile("s_waitcnt lgkmcnt(0)" ::: "memory");      \
    __builtin_amdgcn_sched_barrier(0);                      \
  } while (0)
#define VM6() asm volatile("s_waitcnt vmcnt(6)" ::: "memory")
#define VM0() asm volatile("s_waitcnt vmcnt(0)" ::: "memory")

  // ---- prologue: tile0 {A0,B1,A1,B0} + tile1 {A0,B1,A1}; wait tile0 only ----
  STAGE(0, 0, 0); STAGE(0, 3, 0); STAGE(0, 1, 0); STAGE(0, 2, 0);
  STAGE(1, 0, 1); STAGE(1, 3, 1); STAGE(1, 1, 1);
  VM6();  // 14 loads out -> oldest 8 (tile0) complete; tile1's 3 halves in flight
  BAR();

#pragma unroll 1
  for (int i = 0; i < NIT; ++i) {
    const int t1 = 2 * i + 1;
    const int t2 = 2 * i + 2;
    const int t3 = 2 * i + 3;
    const bool more = (i + 1 < NIT);  // wave-uniform

    // ---- p1: Q(0,0) from buf0 ; stage B0(t1)->buf1 (slot died prev p8) ----
    READ_A(0, 0); READ_B(0, 0);
    STAGE(1, 2, t1);
    BAR(); LGK0();
    MFMA_Q(0);
    BAR();

    // ---- p2: Q(0,1) buf0 (A regs reused) ; stage A0(t2)->buf0 (died p1) ----
    READ_B(0, 1);
    if (more) STAGE(0, 0, t2);
    BAR(); LGK0();
    MFMA_Q(1);
    BAR();

    // ---- p3: Q(1,1) buf0 (B regs reused) ; stage B1(t2)->buf0 (died p2) ----
    READ_A(0, 1);
    if (more) STAGE(0, 3, t2);
    BAR(); LGK0();
    MFMA_Q(3);
    BAR();

    // ---- p4: Q(1,0) buf0 (A regs reused) ; stage A1(t2)->buf0 (died p3) ----
    READ_B(0, 0);
    if (more) STAGE(0, 1, t2);
    BAR(); LGK0();
    MFMA_Q(2);
    // counted wait: completes tile t1's 4 half-tiles, leaves 3 in flight
    if (more) VM6(); else VM0();
    BAR();

    // ---- p5: Q(0,0) from buf1 ; stage B0(t2)->buf0 (died p4) ----
    READ_A(1, 0); READ_B(1, 0);
    if (more) STAGE(0, 2, t2);
    BAR(); LGK0();
    MFMA_Q(0);
    BAR();

    // ---- p6: Q(0,1) buf1 ; stage A0(t3)->buf1 (died p5) ----
    READ_B(1, 1);
    if (more) STAGE(1, 0, t3);
    BAR(); LGK0();
    MFMA_Q(1);
    BAR();

    // ---- p7: Q(1,1) buf1 ; stage B1(t3)->buf1 (died p6) ----
    READ_A(1, 1);
    if (more) STAGE(1, 3, t3);
    BAR(); LGK0();
    MFMA_Q(3);
    BAR();

    // ---- p8: Q(1,0) buf1 ; stage A1(t3)->buf1 (died p7) ----
    READ_B(1, 0);
    if (more) STAGE(1, 1, t3);
    BAR(); LGK0();
    MFMA_Q(2);
    if (more) VM6();  // completes tile t2, leaves t3's {A0,B1,A1} in flight
    BAR();
  }

  // ---- epilogue: C/D layout col = lane&15, row = (lane>>4)*4 + reg ----
  const float scale = scalep[0];
  const int cr = (lane >> 4) << 2;
  const int cc = lane & 15;
#pragma unroll
  for (int qn = 0; qn < 2; ++qn)
#pragma unroll
    for (int ni = 0; ni < 2; ++ni) {
      const int gn = bn + qn * 128 + wqn * 32 + ni * 16 + cc;
      const float bsc = scale * (float)bias[gn];
#pragma unroll
      for (int qm = 0; qm < 2; ++qm) {
#pragma unroll
        for (int mi = 0; mi < 4; ++mi) {
          const int gm = bm + qm * 128 + wqm * 64 + mi * 16 + cr;
#pragma unroll
          for (int r = 0; r < 4; ++r)
            C[(size_t)(gm + r) * TN + gn] = scale * acc[qm * 2 + qn][mi][ni][r] + bsc;
        }
      }
    }
#undef LDSB
#undef STAGE
#undef READ_A
#undef READ_B
#undef MFMA_Q
#undef BAR
#undef LGK0
#undef VM6
#undef VM0
}

// ============================================================================
// fallback (no workspace): previous verified 128x128 fused-convert kernel
// ============================================================================
#define BM 128
#define BN 128
#define BK 64
__global__ __launch_bounds__(256) void qlinear_gemm_fused(
    const float* __restrict__ Xf, const int* __restrict__ Wq,
    const int* __restrict__ bias, const float* __restrict__ scalep,
    float* __restrict__ C) {
  __shared__ __attribute__((aligned(16))) u16 As[BM * BK];
  __shared__ __attribute__((aligned(16))) u16 Bs[BN * BK];

  const int t    = threadIdx.x;
  const int lane = t & 63;
  const int wv   = t >> 6;
  const int waveM = wv & 1;
  const int waveN = wv >> 1;

  const int bid   = (int)(blockIdx.y * gridDim.x + blockIdx.x);
  const int win   = bid >> 8;
  const int local = bid & 255;
  const int bxn   = (win & 7) * 16 + (local & 15);
  const int byn   = (win >> 3) * 16 + (local >> 4);
  const int bm = byn * BM;
  const int bn = bxn * BN;

  f32x4 acc[4][4];
#pragma unroll
  for (int i = 0; i < 4; i++)
#pragma unroll
    for (int j = 0; j < 4; j++) acc[i][j] = (f32x4){0.f, 0.f, 0.f, 0.f};

  for (int kt = 0; kt < TK; kt += BK) {
    __syncthreads();
#pragma unroll
    for (int i = 0; i < 4; i++) {
      const int j = i * 256 + t;
      const int r = j >> 3;
      const int g = (j & 7) ^ (r & 7);
      const float* xs = Xf + (size_t)(bm + r) * TK + kt + g * 8;
      float4 v0 = *(const float4*)xs;
      float4 v1 = *(const float4*)(xs + 4);
      u16x8 oa;
      oa[0] = f2bf(v0.x); oa[1] = f2bf(v0.y); oa[2] = f2bf(v0.z); oa[3] = f2bf(v0.w);
      oa[4] = f2bf(v1.x); oa[5] = f2bf(v1.y); oa[6] = f2bf(v1.z); oa[7] = f2bf(v1.w);
      *(u16x8*)(As + (size_t)j * 8) = oa;
      const int* wsrc = Wq + (size_t)(bn + r) * TK + kt + g * 8;
      int4 w0 = *(const int4*)wsrc;
      int4 w1 = *(const int4*)(wsrc + 4);
      u16x8 ob;
      ob[0] = f2bf((float)w0.x); ob[1] = f2bf((float)w0.y); ob[2] = f2bf((float)w0.z); ob[3] = f2bf((float)w0.w);
      ob[4] = f2bf((float)w1.x); ob[5] = f2bf((float)w1.y); ob[6] = f2bf((float)w1.z); ob[7] = f2bf((float)w1.w);
      *(u16x8*)(Bs + (size_t)j * 8) = ob;
    }
    __syncthreads();

#pragma unroll
    for (int kk = 0; kk < BK; kk += 32) {
      const int kq = (kk >> 3) + (lane >> 4);
      const int px = kq ^ (lane & 7);
      bf16x8 af[4], bfr[4];
#pragma unroll
      for (int mi = 0; mi < 4; mi++) {
        const int r = waveM * 64 + mi * 16 + (lane & 15);
        af[mi] = *(const bf16x8*)(As + r * BK + px * 8);
      }
#pragma unroll
      for (int ni = 0; ni < 4; ni++) {
        const int r = waveN * 64 + ni * 16 + (lane & 15);
        bfr[ni] = *(const bf16x8*)(Bs + r * BK + px * 8);
      }
#pragma unroll
      for (int mi = 0; mi < 4; mi++)
#pragma unroll
        for (int ni = 0; ni < 4; ni++)
          acc[mi][ni] = __builtin_amdgcn_mfma_f32_16x16x32_bf16(af[mi], bfr[ni], acc[mi][ni], 0, 0, 0);
    }
  }

  const float scale = scalep[0];
  const int row0 = bm + waveM * 64 + ((lane >> 4) << 2);
  const int col0 = bn + waveN * 64 + (lane & 15);
#pragma unroll
  for (int ni = 0; ni < 4; ni++) {
    const int gn = col0 + ni * 16;
    const float bsc = scale * (float)bias[gn];
#pragma unroll
    for (int mi = 0; mi < 4; mi++) {
      const int gm = row0 + mi * 16;
#pragma unroll
      for (int r = 0; r < 4; r++) {
        C[(size_t)(gm + r) * TN + gn] = scale * acc[mi][ni][r] + bsc;
      }
    }
  }
}

extern "C" void kernel_launch(void* const* d_in, const int* in_sizes, int n_in,
                              void* d_out, int out_size, void* d_ws, size_t ws_size,
                              hipStream_t stream) {
  const float* x      = (const float*)d_in[0];  // [8192, 4096] fp32
  const int*   w8     = (const int*)d_in[1];    // [16384, 4096] int32 in [-127,127]
  const int*   bias   = (const int*)d_in[2];    // [16384] int32
  const float* scalep = (const float*)d_in[3];  // [1] fp32
  float* out = (float*)d_out;                   // [8192, 16384] fp32

  const size_t xbf_bytes = (size_t)TM * TK * sizeof(u16);  //  64 MiB
  const size_t wbf_bytes = (size_t)TN * TK * sizeof(u16);  // 128 MiB

  if (ws_size >= xbf_bytes + wbf_bytes) {
    u16* xbf = (u16*)d_ws;
    u16* wbf = (u16*)((char*)d_ws + xbf_bytes);
    cvt_x_kernel<<<(TM * TK) / 8 / 256, 256, 0, stream>>>(x, xbf);
    cvt_w_kernel<<<(TN * TK) / 8 / 256, 256, 0, stream>>>(w8, wbf);
    qlinear_gemm256<<<dim3((TM / 256) * (TN / 256)), dim3(512), 0, stream>>>(
        xbf, wbf, bias, scalep, out);
  } else {
    qlinear_gemm_fused<<<dim3(TN / BN, TM / BM), 256, 0, stream>>>(x, w8, bias, scalep, out);
  }
}